// Round 8
// baseline (16.298 us; speedup 1.0000x reference)
//
#include <hip/hip_runtime.h>

#define NJ 32
#define BLK 256

typedef float f2 __attribute__((ext_vector_type(2)));

__device__ __forceinline__ f2 mk2(float x, float y){ f2 r; r.x=x; r.y=y; return r; }
__device__ __forceinline__ f2 perp(f2 v){ return mk2(-v.y, v.x); }   // z-hat x v
__device__ __forceinline__ f2 smul(float a, f2 v){ f2 s = a; return s*v; }

// ---- DPP-based segmented (32-lane) inclusive prefix scan (full-rate VALU) ----
template<int CTRL, int ROW, int BANK>
__device__ __forceinline__ float dpp0(float x) {
    return __int_as_float(
        __builtin_amdgcn_update_dpp(0, __float_as_int(x), CTRL, ROW, BANK, false));
}

__device__ __forceinline__ float scan32(float x) {
    x += dpp0<0x111, 0xf, 0xf>(x);   // row_shr:1
    x += dpp0<0x112, 0xf, 0xf>(x);   // row_shr:2
    x += dpp0<0x114, 0xf, 0xe>(x);   // row_shr:4
    x += dpp0<0x118, 0xf, 0xc>(x);   // row_shr:8
    x += dpp0<0x142, 0xa, 0xf>(x);   // row_bcast:15 -> rows 1,3
    return x;
}

// Shift whole wave down one lane (lane i <- lane i-1); lane 0 gets 0.
__device__ __forceinline__ float wave_shr1(float x) {
    return __int_as_float(
        __builtin_amdgcn_update_dpp(0, __float_as_int(x), 0x138, 0xf, 0xf, false));
}

// Broadcast lane 31 of each 32-lane group (ds_swizzle BitMode, lane'=31).
__device__ __forceinline__ float bcast31(float x) {
    return __int_as_float(
        __builtin_amdgcn_ds_swizzle(__float_as_int(x), 0x03E0));
}

__global__ __launch_bounds__(BLK, 8) void rnea_kernel(
    const float* __restrict__ q,
    const float* __restrict__ qd,
    const float* __restrict__ qdd,
    const float* __restrict__ trans,
    const float* __restrict__ mass,
    const float* __restrict__ com,
    const float* __restrict__ inertia,
    const float* __restrict__ damping,
    float* __restrict__ out,
    int Bn)
{
    const int t    = blockIdx.x * BLK + threadIdx.x;
    const int lane = threadIdx.x & 31;          // joint index
    const int row  = t >> 5;                    // batch row
    if (row >= Bn) return;
    const size_t idx = (size_t)row * NJ + lane; // fully coalesced

    float qj   = q  [idx];
    float qdj  = qd [idx];
    float qddj = qdd[idx];

    // Per-joint constants (L1-hot broadcast lines); z-chain needs only these.
    float m    = mass[lane];
    float cx   = com[3*lane+0], cy = com[3*lane+1];
    f2    mc   = mk2(m*cx, m*cy);
    float i2z  = fmaf(m, cx*cx + cy*cy, inertia[9*lane+8]);   // Ibar_zz
    f2    p    = mk2(trans[3*lane+0], trans[3*lane+1]);
    float damp = damping[lane];

    // ---- Forward pass as prefix sums (world frame). ----
    float phi = scan32(qj);                     // phi_j
    float wI  = scan32(qdj);                    // w_j
    float aI  = scan32(qddj);                   // alpha_j
    float wP  = wI - qdj;                       // w_{j-1}
    float aP  = aI - qddj;                      // alpha_{j-1}

    float c, s;
    __sincosf(phi, &s, &c);                     // at phi_j
    float cp = wave_shr1(c);                    // at phi_{j-1} (prev lane)
    float sp = wave_shr1(s);
    bool seg0 = (lane == 0);
    cp = seg0 ? 1.f : cp;
    sp = seg0 ? 0.f : sp;

    // d_j = Rz(phi_{j-1}) * p_j
    f2 d  = smul(cp, p) + smul(sp, perp(p));    // v_pk
    f2 pd = perp(d);

    // VL_j = sum_{k<=j} w_{k-1} * perp(d_k)
    float VLx = scan32(wP*pd.x);
    float VLy = scan32(wP*pd.y);
    f2 VL = mk2(VLx, VLy);

    // AL_j = sum_{k<=j} [ alpha_{k-1}*perp(d) + qd_k*(VLy, -VLx) ]
    float ALx = scan32(fmaf(aP, pd.x,  qdj*VL.y));
    float ALy = scan32(fmaf(aP, pd.y, -qdj*VL.x));
    f2 AL = mk2(ALx, ALy);

    // ---- Backward pass as suffix sums (world frame; z-chain only). ----
    f2 mcw = smul(c, mc) + smul(s, perp(mc));   // Rz(phi_j) * mc
    f2 J   = mk2(mcw.y, -mcw.x);                // = -perp(mcw)

    // fv_l = m*VL + w * J
    f2 fvl = smul(m, VL) + smul(wI, J);
    // local force terms: fa_l + (0,0,w) x fv_l
    f2 ll  = smul(m, AL) + smul(aI, J) + smul(wI, perp(fvl));

    // F_j = suffix sum via total - prefix + x
    float Px = scan32(ll.x);
    float Py = scan32(ll.y);
    float Fx = bcast31(Px) - Px + ll.x;
    float Fy = bcast31(Py) - Py + ll.y;

    // z-moment chain: a_k = fa_az + (VL x fv_l)z ; b_k = (d x F)z
    float a = fmaf(aI, i2z, mcw.x*AL.y - mcw.y*AL.x + VL.x*fvl.y - VL.y*fvl.x);
    float b = d.x*Fy - d.y*Fx;
    float ab = a + b;
    float Pr = scan32(ab);
    float Nz = bcast31(Pr) - Pr + ab - b;       // suffix(a+b) - b

    out[idx] = fmaf(damp, qdj, Nz);             // tau, fully coalesced
}

extern "C" void kernel_launch(void* const* d_in, const int* in_sizes, int n_in,
                              void* d_out, int out_size, void* d_ws, size_t ws_size,
                              hipStream_t stream) {
    const float* q       = (const float*)d_in[0];
    const float* qd      = (const float*)d_in[1];
    const float* qdd     = (const float*)d_in[2];
    const float* trans   = (const float*)d_in[3];
    const float* mass    = (const float*)d_in[4];
    const float* com     = (const float*)d_in[5];
    const float* inertia = (const float*)d_in[6];
    const float* damping = (const float*)d_in[7];
    float* out = (float*)d_out;

    int Bn = in_sizes[0] / NJ;
    long long threads = (long long)Bn * 32;
    int grid = (int)((threads + BLK - 1) / BLK);
    hipLaunchKernelGGL(rnea_kernel, dim3(grid), dim3(BLK), 0, stream,
                       q, qd, qdd, trans, mass, com, inertia, damping, out, Bn);
}

// Round 9
// 15.570 us; speedup vs baseline: 1.0468x; 1.0468x over previous
//
#include <hip/hip_runtime.h>

#define NJ 32
#define BLK 256

// ---- DPP-based segmented (32-lane) inclusive prefix scan (full-rate VALU).
// LLVM AMDGPUAtomicOptimizer pattern; old=0 + bound_ctrl=false makes invalid
// source lanes contribute 0, which is the scan identity. GCNDPPCombine fuses
// each mov_dpp+add into v_add_f32_dpp.
template<int CTRL, int ROW, int BANK>
__device__ __forceinline__ float dpp0(float x) {
    return __int_as_float(
        __builtin_amdgcn_update_dpp(0, __float_as_int(x), CTRL, ROW, BANK, false));
}

__device__ __forceinline__ float scan32(float x) {
    x += dpp0<0x111, 0xf, 0xf>(x);   // row_shr:1
    x += dpp0<0x112, 0xf, 0xf>(x);   // row_shr:2
    x += dpp0<0x114, 0xf, 0xe>(x);   // row_shr:4
    x += dpp0<0x118, 0xf, 0xc>(x);   // row_shr:8
    x += dpp0<0x142, 0xa, 0xf>(x);   // row_bcast:15 -> rows 1,3
    return x;
}

// Shift whole wave down one lane (lane i <- lane i-1); wave lane 0 gets 0.
__device__ __forceinline__ float wave_shr1(float x) {
    return __int_as_float(
        __builtin_amdgcn_update_dpp(0, __float_as_int(x), 0x138, 0xf, 0xf, false));
}

// Broadcast lane 31 of each 32-lane group (ds_swizzle BitMode, lane'=31).
__device__ __forceinline__ float bcast31(float x) {
    return __int_as_float(
        __builtin_amdgcn_ds_swizzle(__float_as_int(x), 0x03E0));
}

struct Consts {
    float m, mcx, mcy, i2z, px, py, damp;
};

// One batch row (32 joints across a 32-lane segment) -> tau for this lane.
__device__ __forceinline__ float tau_row(float qj, float qdj, float qddj,
                                         bool seg0, const Consts& C)
{
    // ---- Forward pass as prefix sums (world frame). ----
    float phi = scan32(qj);                     // phi_j
    float wI  = scan32(qdj);                    // w_j
    float aI  = scan32(qddj);                   // alpha_j
    float wP  = wI - qdj;                       // w_{j-1}
    float aP  = aI - qddj;                      // alpha_{j-1}

    float c, s;
    __sincosf(phi, &s, &c);                     // at phi_j
    float cp = wave_shr1(c);                    // at phi_{j-1} (prev lane)
    float sp = wave_shr1(s);
    cp = seg0 ? 1.f : cp;
    sp = seg0 ? 0.f : sp;

    // d_j = Rz(phi_{j-1}) * p_j   (x,y only)
    float dx = cp*C.px - sp*C.py;
    float dy = sp*C.px + cp*C.py;

    // VL_j = sum_{k<=j} w_{k-1} * (-dy_k, dx_k)
    float VLx = scan32(-wP*dy);
    float VLy = scan32( wP*dx);

    // AL_j = sum_{k<=j} [ alpha_{k-1}*(-dy,dx) + qd_k*(VLy_k, -VLx_k) ]
    float ALx = scan32(fmaf(-aP, dy,  qdj*VLy));
    float ALy = scan32(fmaf( aP, dx, -qdj*VLx));

    // ---- Backward pass as suffix sums (world frame; z-chain only). ----
    float mcwx = c*C.mcx - s*C.mcy;             // Rz(phi_j) * mc
    float mcwy = s*C.mcx + c*C.mcy;

    // fv_l = m*VL + mc_w x (0,0,w)
    float fv_lx = fmaf(C.m, VLx,  wI*mcwy);
    float fv_ly = fmaf(C.m, VLy, -wI*mcwx);

    // local force terms: fa_l + (0,0,w) x fv_l   (x,y)
    float llx = fmaf(C.m, ALx, fmaf( aI, mcwy, -wI*fv_ly));
    float lly = fmaf(C.m, ALy, fmaf(-aI, mcwx,  wI*fv_lx));

    // F_j = suffix sum via segment total - prefix + x
    float Px = scan32(llx);
    float Py = scan32(lly);
    float Fx = bcast31(Px) - Px + llx;
    float Fy = bcast31(Py) - Py + lly;

    // z-moment chain: a_k = fa_az + (VL x fv_l)z ; b_k = (d x F)z
    float a = fmaf(aI, C.i2z, mcwx*ALy - mcwy*ALx + VLx*fv_ly - VLy*fv_lx);
    float b = dx*Fy - dy*Fx;
    float ab = a + b;
    float Pr = scan32(ab);
    float Nz = bcast31(Pr) - Pr + ab - b;       // suffix(a+b) - b

    return fmaf(C.damp, qdj, Nz);
}

__global__ __launch_bounds__(BLK, 4) void rnea_kernel(
    const float* __restrict__ q,
    const float* __restrict__ qd,
    const float* __restrict__ qdd,
    const float* __restrict__ trans,
    const float* __restrict__ mass,
    const float* __restrict__ com,
    const float* __restrict__ inertia,
    const float* __restrict__ damping,
    float* __restrict__ out,
    int Bn)
{
    const int t    = blockIdx.x * BLK + threadIdx.x;
    const int lane = threadIdx.x & 31;          // joint index
    const int half = Bn >> 1;
    const int r0   = t >> 5;                    // first batch row
    if (r0 >= half) return;
    const size_t i0 = (size_t)r0 * NJ + lane;   // coalesced
    const size_t i1 = i0 + (size_t)half * NJ;   // coalesced (second row block)

    // Issue all global loads first (latency overlap across both rows).
    float q0   = q  [i0], q1   = q  [i1];
    float qd0  = qd [i0], qd1  = qd [i1];
    float qdd0 = qdd[i0], qdd1 = qdd[i1];

    // Per-joint constants, gathered once, shared by both rows.
    Consts C;
    C.m    = mass[lane];
    float cx = com[3*lane+0], cy = com[3*lane+1];
    C.mcx  = C.m*cx;  C.mcy = C.m*cy;
    C.i2z  = fmaf(C.m, cx*cx + cy*cy, inertia[9*lane+8]);   // Ibar_zz
    C.px   = trans[3*lane+0];
    C.py   = trans[3*lane+1];
    C.damp = damping[lane];

    const bool seg0 = (lane == 0);

    // Two independent pipelines; compiler interleaves for ILP across the
    // serial 5-step DPP scan chains.
    float t0 = tau_row(q0, qd0, qdd0, seg0, C);
    float t1 = tau_row(q1, qd1, qdd1, seg0, C);

    out[i0] = t0;
    out[i1] = t1;
}

extern "C" void kernel_launch(void* const* d_in, const int* in_sizes, int n_in,
                              void* d_out, int out_size, void* d_ws, size_t ws_size,
                              hipStream_t stream) {
    const float* q       = (const float*)d_in[0];
    const float* qd      = (const float*)d_in[1];
    const float* qdd     = (const float*)d_in[2];
    const float* trans   = (const float*)d_in[3];
    const float* mass    = (const float*)d_in[4];
    const float* com     = (const float*)d_in[5];
    const float* inertia = (const float*)d_in[6];
    const float* damping = (const float*)d_in[7];
    float* out = (float*)d_out;

    int Bn = in_sizes[0] / NJ;
    long long threads = (long long)(Bn/2) * 32;
    int grid = (int)((threads + BLK - 1) / BLK);
    hipLaunchKernelGGL(rnea_kernel, dim3(grid), dim3(BLK), 0, stream,
                       q, qd, qdd, trans, mass, com, inertia, damping, out, Bn);
}